// Round 5
// baseline (446.363 us; speedup 1.0000x reference)
//
#include <hip/hip_runtime.h>
#include <hip/hip_bf16.h>
#include <math.h>

// ---------------------------------------------------------------------------
// MLA forward, bf16 MFMA; attn with reg-prefetch pipeline + XCD-local blocks.
// B=2 S=2048 H=2048 nh=16 hd=128 rd=64 L=256
// ---------------------------------------------------------------------------

typedef __attribute__((ext_vector_type(8))) short bf16x8;
typedef __attribute__((ext_vector_type(4))) float f32x4;
typedef unsigned int u32;

#define MFMA16(a, b, c) __builtin_amdgcn_mfma_f32_16x16x32_bf16(a, b, c, 0, 0, 0)

__device__ __forceinline__ short f2bs(float f) {
  __hip_bfloat16 h = __float2bfloat16(f);
  return *reinterpret_cast<short*>(&h);
}
__device__ __forceinline__ float bs2f(short s) {
  union { unsigned int u; float f; } v;
  v.u = ((unsigned int)(unsigned short)s) << 16;
  return v.f;
}
__device__ __forceinline__ u32 fbits(float f) {
  union { float f; u32 u; } v; v.f = f; return v.u;
}

__device__ __forceinline__ void async16(const void* g, void* l) {
  __builtin_amdgcn_global_load_lds(
      (const __attribute__((address_space(1))) u32*)(unsigned long long)g,
      (__attribute__((address_space(3))) u32*)(unsigned int)(unsigned long long)l,
      16, 0, 0);
}
__device__ __forceinline__ void wait_vm0() {
  __builtin_amdgcn_s_waitcnt(0x0f70);  // vmcnt(0)
}

// ---------------- fused prep: cast hs + all weight transposes --------------
__device__ __forceinline__ void wtrans_tile(const float* __restrict__ W,
                                            short* __restrict__ Wt, int K, int N,
                                            int bx, int by, int tid) {
  __shared__ float t[32][33];
  int k0 = by * 32, n0 = bx * 32;
#pragma unroll
  for (int i = 0; i < 4; ++i) {
    int idx = tid + i * 256;
    int r = idx >> 5, c = idx & 31;
    t[r][c] = W[(size_t)(k0 + r) * N + n0 + c];
  }
  __syncthreads();
#pragma unroll
  for (int i = 0; i < 4; ++i) {
    int idx = tid + i * 256;
    int r = idx >> 5, c = idx & 31;
    Wt[(size_t)(n0 + r) * K + k0 + c] = f2bs(t[c][r]);
  }
}

__global__ __launch_bounds__(256) void prep_all(
    const float* __restrict__ hs, const float* __restrict__ Wkvd,
    const float* __restrict__ Wqd, const float* __restrict__ Wku,
    const float* __restrict__ Wqu, const float* __restrict__ Wvu,
    const float* __restrict__ Wrk, const float* __restrict__ Wrq,
    const float* __restrict__ Wo, short* __restrict__ hs_b,
    short* __restrict__ W1t, short* __restrict__ W2t,
    short* __restrict__ W3t, short* __restrict__ Wo_t) {
  const int b = blockIdx.x, tid = threadIdx.x;
  if (b < 8192) {
    int i = (b * 256 + tid) * 4;
    float4 v = *(const float4*)(hs + i);
    short4 o;
    o.x = f2bs(v.x); o.y = f2bs(v.y); o.z = f2bs(v.z); o.w = f2bs(v.w);
    *(short4*)(hs_b + i) = o;
  } else if (b < 8704) {
    int l = b - 8192; wtrans_tile(Wkvd, W1t, 2048, 256, l & 7, l >> 3, tid);
  } else if (b < 9216) {
    int l = b - 8704; wtrans_tile(Wqd, W1t + 256 * 2048, 2048, 256, l & 7, l >> 3, tid);
  } else if (b < 11264) {
    int l = b - 9216; wtrans_tile(Wrk, W1t + 512 * 2048, 2048, 1024, l & 31, l >> 5, tid);
  } else if (b < 11520) {
    int l = b - 11264; wtrans_tile(Wku, W2t, 256, 1024, l & 31, l >> 5, tid);
  } else if (b < 12032) {
    int l = b - 11520; wtrans_tile(Wvu, W2t + 1024 * 256, 256, 2048, l & 63, l >> 6, tid);
  } else if (b < 12288) {
    int l = b - 12032; wtrans_tile(Wqu, W3t, 256, 1024, l & 31, l >> 5, tid);
  } else if (b < 12544) {
    int l = b - 12288; wtrans_tile(Wrq, W3t + 1024 * 256, 256, 1024, l & 31, l >> 5, tid);
  } else {
    int l = b - 12544; wtrans_tile(Wo, Wo_t, 2048, 2048, l & 63, l >> 6, tid);
  }
}

// ---------------- bf16 MFMA GEMM, swizzled staging: C = A @ Bt^T -----------
__device__ __forceinline__ void cstore(float v, float* p) { *p = v; }
__device__ __forceinline__ void cstore(float v, short* p) { *p = f2bs(v); }

template <typename CT>
__global__ __launch_bounds__(256) void gemm_bt(const short* __restrict__ A, int lda,
                                               const short* __restrict__ Bt, int ldb,
                                               CT* __restrict__ C, int ldc, int K) {
  __shared__ short As[128 * 32];
  __shared__ short Bs[128 * 32];
  const int tid = threadIdx.x;
  const int wave = tid >> 6, lane = tid & 63;
  const int quad = lane >> 4, l15 = lane & 15;
  const int wm = wave & 1, wn = wave >> 1;
  const int row0 = blockIdx.y * 128, col0 = blockIdx.x * 128;
  const int ar = tid >> 2;
  const int ac = (((tid & 3) ^ ((tid >> 2) & 3) ^ ((tid >> 4) & 3))) * 8;
  const short* Ag = A + (size_t)(row0 + ar) * lda + ac;
  const short* Bg = Bt + (size_t)(col0 + ar) * ldb + ac;
  const int sw = ((quad ^ (l15 & 3) ^ ((l15 >> 2) & 3))) * 8;

  f32x4 acc[4][4];
#pragma unroll
  for (int i = 0; i < 4; ++i)
#pragma unroll
    for (int j = 0; j < 4; ++j) acc[i][j] = {0.f, 0.f, 0.f, 0.f};

  for (int k0 = 0; k0 < K; k0 += 32) {
    __syncthreads();
    async16(Ag + k0, &As[tid * 8]);
    async16(Ag + (size_t)64 * lda + k0, &As[2048 + tid * 8]);
    async16(Bg + k0, &Bs[tid * 8]);
    async16(Bg + (size_t)64 * ldb + k0, &Bs[2048 + tid * 8]);
    wait_vm0();
    __syncthreads();
    bf16x8 af[4], bfr[4];
#pragma unroll
    for (int i = 0; i < 4; ++i) {
      af[i]  = *(const bf16x8*)&As[(wm * 64 + i * 16 + l15) * 32 + sw];
      bfr[i] = *(const bf16x8*)&Bs[(wn * 64 + i * 16 + l15) * 32 + sw];
    }
#pragma unroll
    for (int i = 0; i < 4; ++i)
#pragma unroll
      for (int j = 0; j < 4; ++j)
        acc[i][j] = MFMA16(af[i], bfr[j], acc[i][j]);
  }
#pragma unroll
  for (int i = 0; i < 4; ++i)
#pragma unroll
    for (int j = 0; j < 4; ++j)
#pragma unroll
      for (int r = 0; r < 4; ++r) {
        int row = row0 + wm * 64 + i * 16 + quad * 4 + r;
        int col = col0 + wn * 64 + j * 16 + l15;
        cstore(acc[i][j][r], &C[(size_t)row * ldc + col]);
      }
}

// ---------------- RoPE + concat + head-major pack (bf16) -------------------
__global__ __launch_bounds__(256) void rope_pack(
    const short* __restrict__ c3, const short* __restrict__ c2,
    const short* __restrict__ c1, short* __restrict__ qf,
    short* __restrict__ kf) {
  const float QSCALE = 0.08838834764831845f * 1.4426950408889634f;
  int idx = blockIdx.x * 256 + threadIdx.x;
  int m = idx >> 11;
  int col = idx & 2047;
  int h = col >> 7;
  int j = col & 127;
  int b = m >> 11, s = m & 2047;
  float oq, ok;
  if (j < 64) {
    oq = bs2f(c3[(size_t)m * 2048 + h * 64 + j]);
    ok = bs2f(c2[(size_t)m * 3072 + h * 64 + j]);
  } else {
    int jr = j - 64;
    int f = jr & 31;
    float ang = (float)s * __expf(-0.2878231366242557f * (float)f);
    float c = __cosf(ang), sn = __sinf(ang);
    size_t qb = (size_t)m * 2048 + 1024 + h * 64;
    size_t kb = (size_t)m * 1536 + 512 + h * 64;
    float xq = bs2f(c3[qb + jr]), xk = bs2f(c1[kb + jr]);
    float rq, rk;
    if (jr < 32) { rq = -bs2f(c3[qb + jr + 32]); rk = -bs2f(c1[kb + jr + 32]); }
    else         { rq =  bs2f(c3[qb + jr - 32]); rk =  bs2f(c1[kb + jr - 32]); }
    oq = fmaf(xq, c, rq * sn);
    ok = fmaf(xk, c, rk * sn);
  }
  size_t dst = (((size_t)b * 16 + h) * 2048 + s) * 128 + j;
  qf[dst] = f2bs(oq * QSCALE);
  kf[dst] = f2bs(ok);
}

// ---------------- V transpose: C2 col 1024 (ld 3072) -> vt(b,h,128,s) ------
__global__ __launch_bounds__(256) void vtrans(const short* __restrict__ c2,
                                              short* __restrict__ vt) {
  __shared__ short t[64][72];
  int s0 = blockIdx.x * 64, d0 = blockIdx.y * 64, bh = blockIdx.z;
  int b = bh >> 4, h = bh & 15;
#pragma unroll
  for (int i = 0; i < 16; ++i) {
    int idx = threadIdx.x + i * 256;
    int r = idx >> 6, c = idx & 63;
    t[r][c] = c2[(size_t)(b * 2048 + s0 + r) * 3072 + 1024 + h * 128 + d0 + c];
  }
  __syncthreads();
#pragma unroll
  for (int i = 0; i < 16; ++i) {
    int idx = threadIdx.x + i * 256;
    int r = idx >> 6, c = idx & 63;
    vt[((size_t)bh * 128 + d0 + r) * 2048 + s0 + c] = t[c][r];
  }
}

// ---------------- balanced split-K flash attention -------------------------
// Reg-prefetch pipeline: tile k+1 global->VGPR during compute of tile k, then
// VGPR->LDS after the barrier. XCD-local bh mapping for L2 reuse.
__global__ __launch_bounds__(256) void attn_split(const short* __restrict__ qf,
                                                  const short* __restrict__ kf,
                                                  const short* __restrict__ vt,
                                                  short* __restrict__ part,
                                                  float2* __restrict__ ml) {
  __shared__ short Ks[64 * 128];   // [kpos][d], chunk-swizzled
  __shared__ short Vs[128 * 64];   // [d][kpos], chunk-swizzled
  __shared__ short Pw[4][32 * 72];
  // XCD-local remap: consecutive blocks round-robin XCDs; give each XCD 4 bh.
  const int lid = blockIdx.x;
  const int bh = (lid & 7) * 4 + ((lid >> 3) & 3);
  const int x = lid >> 5;
  const int tid = threadIdx.x;
  const int wave = tid >> 6, lane = tid & 63;
  const int quad = lane >> 4, l15 = lane & 15;
  const int krow_l = tid >> 4;
  const int kcol_sw = ((tid & 15) ^ krow_l) * 8;
  const int vrow_l = tid >> 3;
  const int vcol_sw = ((tid & 7) ^ (vrow_l & 7)) * 8;
  const short* kgB = kf + (((size_t)bh * 2048) + krow_l) * 128 + kcol_sw;
  const short* vgB = vt + ((size_t)bh * 128 + vrow_l) * 2048 + vcol_sw;

  uint4 kr4[4], vr4[4];

  for (int pass = 0; pass < 2; ++pass) {
    const int qt = pass == 0 ? x : 15 - x;
    const int ks = pass == 0 ? 0 : qt + 1;
    const int ke = (qt + 1) << pass;
    const int q0w = qt * 128 + wave * 32;

    bf16x8 qfr[2][4];
#pragma unroll
    for (int mi = 0; mi < 2; ++mi) {
      const short* qp = qf + (((size_t)bh * 2048) + q0w + mi * 16 + l15) * 128;
#pragma unroll
      for (int kc = 0; kc < 4; ++kc)
        qfr[mi][kc] = *(const bf16x8*)(qp + kc * 32 + quad * 8);
    }
    float m_i[2] = {-INFINITY, -INFINITY};
    float l_i[2] = {0.f, 0.f};
    f32x4 O[2][8];
#pragma unroll
    for (int mi = 0; mi < 2; ++mi)
#pragma unroll
      for (int dt = 0; dt < 8; ++dt) O[mi][dt] = {0.f, 0.f, 0.f, 0.f};

    // prologue: fetch first tile into regs, stage to LDS
    {
      const short* kg = kgB + (size_t)ks * 64 * 128;
      const short* vg = vgB + ks * 64;
#pragma unroll
      for (int i = 0; i < 4; ++i) {
        kr4[i] = *(const uint4*)(kg + (size_t)i * 16 * 128);
        vr4[i] = *(const uint4*)(vg + (size_t)i * 32 * 2048);
      }
    }
    __syncthreads();  // previous consumers of Ks/Vs done
#pragma unroll
    for (int i = 0; i < 4; ++i) {
      *(uint4*)&Ks[i * 2048 + tid * 8] = kr4[i];
      *(uint4*)&Vs[i * 2048 + tid * 8] = vr4[i];
    }
    __syncthreads();

    for (int kt = ks; kt < ke; ++kt) {
      const int k0 = kt * 64;
      const bool more = (kt + 1 < ke);
      if (more) {  // prefetch next tile into regs (latency overlaps compute)
        const short* kg = kgB + (size_t)(k0 + 64) * 128;
        const short* vg = vgB + (k0 + 64);
#pragma unroll
        for (int i = 0; i < 4; ++i) {
          kr4[i] = *(const uint4*)(kg + (size_t)i * 16 * 128);
          vr4[i] = *(const uint4*)(vg + (size_t)i * 32 * 2048);
        }
      }

      // S^T = K @ Q^T  (m=kpos 64, n=qrow 32); lane col l15 = q-row
      f32x4 St[2][4];
#pragma unroll
      for (int mi = 0; mi < 2; ++mi)
#pragma unroll
        for (int j = 0; j < 4; ++j) St[mi][j] = {0.f, 0.f, 0.f, 0.f};
#pragma unroll
      for (int kc = 0; kc < 4; ++kc) {
        bf16x8 kb[4];
#pragma unroll
        for (int j = 0; j < 4; ++j)
          kb[j] = *(const bf16x8*)&Ks[(j * 16 + l15) * 128 +
                                      (((kc * 4 + quad) ^ l15) & 15) * 8];
#pragma unroll
        for (int mi = 0; mi < 2; ++mi)
#pragma unroll
          for (int j = 0; j < 4; ++j)
            St[mi][j] = MFMA16(kb[j], qfr[mi][kc], St[mi][j]);
      }

      if (kt >= 2 * qt) {
#pragma unroll
        for (int mi = 0; mi < 2; ++mi)
#pragma unroll
          for (int j = 0; j < 4; ++j)
#pragma unroll
            for (int r = 0; r < 4; ++r)
              if (k0 + j * 16 + quad * 4 + r > q0w + mi * 16 + l15)
                St[mi][j][r] = -INFINITY;
      }

      float alpha[2];
#pragma unroll
      for (int mi = 0; mi < 2; ++mi) {
        float mt = -INFINITY;
#pragma unroll
        for (int j = 0; j < 4; ++j)
#pragma unroll
          for (int r = 0; r < 4; ++r) mt = fmaxf(mt, St[mi][j][r]);
        mt = fmaxf(mt, __shfl_xor(mt, 16));
        mt = fmaxf(mt, __shfl_xor(mt, 32));
        float mold = m_i[mi];
        float mnew = fmaxf(mold, mt);
        float msafe = (mnew == -INFINITY) ? 0.f : mnew;
        alpha[mi] = __builtin_amdgcn_exp2f(mold - msafe);
        float ps = 0.f;
#pragma unroll
        for (int j = 0; j < 4; ++j)
#pragma unroll
          for (int r = 0; r < 4; ++r) {
            float p = __builtin_amdgcn_exp2f(St[mi][j][r] - msafe);
            St[mi][j][r] = p;
            ps += p;
          }
        ps += __shfl_xor(ps, 16);
        ps += __shfl_xor(ps, 32);
        m_i[mi] = mnew;
        l_i[mi] = l_i[mi] * alpha[mi] + ps;
#pragma unroll
        for (int dt = 0; dt < 8; ++dt)
#pragma unroll
          for (int r = 0; r < 4; ++r) O[mi][dt][r] *= alpha[mi];
      }

      // P (truncated bf16) -> per-wave LDS
#pragma unroll
      for (int mi = 0; mi < 2; ++mi)
#pragma unroll
        for (int j = 0; j < 4; ++j) {
          u32 u0 = (fbits(St[mi][j][1]) & 0xffff0000u) | (fbits(St[mi][j][0]) >> 16);
          u32 u1 = (fbits(St[mi][j][3]) & 0xffff0000u) | (fbits(St[mi][j][2]) >> 16);
          uint2 pk; pk.x = u0; pk.y = u1;
          *(uint2*)&Pw[wave][(mi * 16 + l15) * 72 + j * 16 + quad * 4] = pk;
        }

      // O^T += V^T-frag @ P-frag
#pragma unroll
      for (int kc2 = 0; kc2 < 2; ++kc2) {
        bf16x8 pa[2];
#pragma unroll
        for (int mi = 0; mi < 2; ++mi)
          pa[mi] = *(const bf16x8*)&Pw[wave][(mi * 16 + l15) * 72 + kc2 * 32 + quad * 8];
#pragma unroll
        for (int dt = 0; dt < 8; ++dt) {
          bf16x8 vb = *(const bf16x8*)&Vs[(dt * 16 + l15) * 64 +
                                          (((kc2 * 4 + quad) ^ (l15 & 7)) & 7) * 8];
#pragma unroll
          for (int mi = 0; mi < 2; ++mi)
            O[mi][dt] = MFMA16(vb, pa[mi], O[mi][dt]);
        }
      }

      __syncthreads();  // all waves done with Ks/Vs
      if (more) {
#pragma unroll
        for (int i = 0; i < 4; ++i) {
          *(uint4*)&Ks[i * 2048 + tid * 8] = kr4[i];
          *(uint4*)&Vs[i * 2048 + tid * 8] = vr4[i];
        }
        __syncthreads();
      }
    }

    // store partial O as bf16: [qrow][d]
    const int pidx = (bh * 16 + qt) * 2 + pass;
    short* pb = part + (size_t)pidx * 128 * 128;
#pragma unroll
    for (int mi = 0; mi < 2; ++mi) {
      int qrow = wave * 32 + mi * 16 + l15;
#pragma unroll
      for (int dt = 0; dt < 8; ++dt) {
        short4 o;
        o.x = f2bs(O[mi][dt][0]); o.y = f2bs(O[mi][dt][1]);
        o.z = f2bs(O[mi][dt][2]); o.w = f2bs(O[mi][dt][3]);
        *(short4*)&pb[(size_t)qrow * 128 + dt * 16 + quad * 4] = o;
      }
    }
    if (quad == 0) {
#pragma unroll
      for (int mi = 0; mi < 2; ++mi) {
        float2 v; v.x = m_i[mi]; v.y = l_i[mi];
        ml[pidx * 128 + wave * 32 + mi * 16 + l15] = v;
      }
    }
  }
}

// ---------------- merge two partials per q-tile ----------------------------
__global__ __launch_bounds__(256) void attn_merge(const short* __restrict__ part,
                                                  const float2* __restrict__ ml,
                                                  short* __restrict__ y) {
  const int qt = blockIdx.x, bh = blockIdx.y;
  const int b = bh >> 4, h = bh & 15;
  const int row = threadIdx.x >> 1, d0 = (threadIdx.x & 1) * 64;
  const int p1 = (bh * 16 + qt) * 2, p2 = p1 + 1;
  float2 a = ml[p1 * 128 + row], c = ml[p2 * 128 + row];
  float m = fmaxf(a.x, c.x);
  float a1 = __builtin_amdgcn_exp2f(a.x - m);
  float a2 = __builtin_amdgcn_exp2f(c.x - m);
  float invl = 1.f / (a.y * a1 + c.y * a2);
  a1 *= invl; a2 *= invl;
  const short* s1 = part + ((size_t)p1 * 128 + row) * 128 + d0;
  const short* s2 = part + ((size_t)p2 * 128 + row) * 128 + d0;
  short* yp = y + (((size_t)b * 2048 + qt * 128 + row) * 16 + h) * 128 + d0;
#pragma unroll
  for (int j = 0; j < 16; ++j) {
    short4 v1 = *(const short4*)(s1 + j * 4);
    short4 v2 = *(const short4*)(s2 + j * 4);
    short4 o;
    o.x = f2bs(bs2f(v1.x) * a1 + bs2f(v2.x) * a2);
    o.y = f2bs(bs2f(v1.y) * a1 + bs2f(v2.y) * a2);
    o.z = f2bs(bs2f(v1.z) * a1 + bs2f(v2.z) * a2);
    o.w = f2bs(bs2f(v1.w) * a1 + bs2f(v2.w) * a2);
    *(short4*)(yp + j * 4) = o;
  }
}

extern "C" void kernel_launch(void* const* d_in, const int* in_sizes, int n_in,
                              void* d_out, int out_size, void* d_ws, size_t ws_size,
                              hipStream_t stream) {
  const float* hs   = (const float*)d_in[0];
  const float* Wkvd = (const float*)d_in[1];
  const float* Wqd  = (const float*)d_in[2];
  const float* Wku  = (const float*)d_in[3];
  const float* Wqu  = (const float*)d_in[4];
  const float* Wvu  = (const float*)d_in[5];
  const float* Wrk  = (const float*)d_in[6];
  const float* Wrq  = (const float*)d_in[7];
  const float* Wo   = (const float*)d_in[8];
  float* out = (float*)d_out;
  char* ws = (char*)d_ws;
  const size_t MB = 1024ull * 1024ull;

  short* hs_b = (short*)(ws + 0 * MB);     // 16 MB
  short* W1t  = (short*)(ws + 16 * MB);    // (1536,2048): kvd|qd|rk ^T
  short* W2t  = (short*)(ws + 22 * MB);    // (3072,256): ku|vu ^T
  short* W3t  = (short*)(ws + 24 * MB);    // (2048,256): qu|rq ^T
  short* C1   = (short*)(ws + 25 * MB);    // (4096,1536): kv_d|q_d|k_r
  short* C2   = (short*)(ws + 37 * MB);    // (4096,3072): k_c|v
  short* C3   = (short*)(ws + 61 * MB);    // (4096,2048): q_c|q_r
  short* Wo_t = (short*)(ws + 77 * MB);    // (2048,2048)
  short* q_f  = (short*)(ws + 85 * MB);    // (32,2048,128)
  short* k_f  = (short*)(ws + 101 * MB);
  short* v_t  = (short*)(ws + 117 * MB);   // (32,128,2048)
  short* y_b  = (short*)(ws + 133 * MB);   // (b,s,h,d)
  short*  partb = (short*)(ws + 0 * MB);   // overlay: 1024x128x128 bf16 (32 MB)
  float2* mlb   = (float2*)(ws + 32 * MB); // 1 MB

  dim3 blk(256);
  prep_all<<<dim3(16640), blk, 0, stream>>>(hs, Wkvd, Wqd, Wku, Wqu, Wvu, Wrk,
                                            Wrq, Wo, hs_b, W1t, W2t, W3t, Wo_t);

  gemm_bt<short><<<dim3(12, 32), blk, 0, stream>>>(hs_b, 2048, W1t, 2048, C1, 1536, 2048);
  gemm_bt<short><<<dim3(24, 32), blk, 0, stream>>>(C1, 1536, W2t, 256, C2, 3072, 256);
  gemm_bt<short><<<dim3(16, 32), blk, 0, stream>>>(C1 + 256, 1536, W3t, 256, C3, 2048, 256);

  rope_pack<<<dim3(32768), blk, 0, stream>>>(C3, C2, C1, q_f, k_f);
  vtrans<<<dim3(32, 2, 32), blk, 0, stream>>>(C2, v_t);

  attn_split<<<dim3(512), blk, 0, stream>>>(q_f, k_f, v_t, partb, mlb);
  attn_merge<<<dim3(16, 32), blk, 0, stream>>>(partb, mlb, y_b);

  gemm_bt<float><<<dim3(16, 32), blk, 0, stream>>>(y_b, 2048, Wo_t, 2048, out, 2048, 2048);
}

// Round 6
// 386.470 us; speedup vs baseline: 1.1550x; 1.1550x over previous
//
#include <hip/hip_runtime.h>
#include <hip/hip_bf16.h>
#include <math.h>

// ---------------------------------------------------------------------------
// MLA forward, bf16 MFMA; attn: async LDS double-buffer + XCD-local blocks.
// B=2 S=2048 H=2048 nh=16 hd=128 rd=64 L=256
// ---------------------------------------------------------------------------

typedef __attribute__((ext_vector_type(8))) short bf16x8;
typedef __attribute__((ext_vector_type(4))) float f32x4;
typedef unsigned int u32;

#define MFMA16(a, b, c) __builtin_amdgcn_mfma_f32_16x16x32_bf16(a, b, c, 0, 0, 0)

__device__ __forceinline__ short f2bs(float f) {
  __hip_bfloat16 h = __float2bfloat16(f);
  return *reinterpret_cast<short*>(&h);
}
__device__ __forceinline__ float bs2f(short s) {
  union { unsigned int u; float f; } v;
  v.u = ((unsigned int)(unsigned short)s) << 16;
  return v.f;
}
__device__ __forceinline__ u32 fbits(float f) {
  union { float f; u32 u; } v; v.f = f; return v.u;
}

__device__ __forceinline__ void async16(const void* g, void* l) {
  __builtin_amdgcn_global_load_lds(
      (const __attribute__((address_space(1))) u32*)(unsigned long long)g,
      (__attribute__((address_space(3))) u32*)(unsigned int)(unsigned long long)l,
      16, 0, 0);
}
__device__ __forceinline__ void wait_vm0() {
  __builtin_amdgcn_s_waitcnt(0x0f70);  // vmcnt(0) only
}

// ---------------- fused prep: cast hs + all weight transposes --------------
__device__ __forceinline__ void wtrans_tile(const float* __restrict__ W,
                                            short* __restrict__ Wt, int K, int N,
                                            int bx, int by, int tid) {
  __shared__ float t[32][33];
  int k0 = by * 32, n0 = bx * 32;
#pragma unroll
  for (int i = 0; i < 4; ++i) {
    int idx = tid + i * 256;
    int r = idx >> 5, c = idx & 31;
    t[r][c] = W[(size_t)(k0 + r) * N + n0 + c];
  }
  __syncthreads();
#pragma unroll
  for (int i = 0; i < 4; ++i) {
    int idx = tid + i * 256;
    int r = idx >> 5, c = idx & 31;
    Wt[(size_t)(n0 + r) * K + k0 + c] = f2bs(t[c][r]);
  }
}

__global__ __launch_bounds__(256) void prep_all(
    const float* __restrict__ hs, const float* __restrict__ Wkvd,
    const float* __restrict__ Wqd, const float* __restrict__ Wku,
    const float* __restrict__ Wqu, const float* __restrict__ Wvu,
    const float* __restrict__ Wrk, const float* __restrict__ Wrq,
    const float* __restrict__ Wo, short* __restrict__ hs_b,
    short* __restrict__ W1t, short* __restrict__ W2t,
    short* __restrict__ W3t, short* __restrict__ Wo_t) {
  const int b = blockIdx.x, tid = threadIdx.x;
  if (b < 8192) {
    int i = (b * 256 + tid) * 4;
    float4 v = *(const float4*)(hs + i);
    short4 o;
    o.x = f2bs(v.x); o.y = f2bs(v.y); o.z = f2bs(v.z); o.w = f2bs(v.w);
    *(short4*)(hs_b + i) = o;
  } else if (b < 8704) {
    int l = b - 8192; wtrans_tile(Wkvd, W1t, 2048, 256, l & 7, l >> 3, tid);
  } else if (b < 9216) {
    int l = b - 8704; wtrans_tile(Wqd, W1t + 256 * 2048, 2048, 256, l & 7, l >> 3, tid);
  } else if (b < 11264) {
    int l = b - 9216; wtrans_tile(Wrk, W1t + 512 * 2048, 2048, 1024, l & 31, l >> 5, tid);
  } else if (b < 11520) {
    int l = b - 11264; wtrans_tile(Wku, W2t, 256, 1024, l & 31, l >> 5, tid);
  } else if (b < 12032) {
    int l = b - 11520; wtrans_tile(Wvu, W2t + 1024 * 256, 256, 2048, l & 63, l >> 6, tid);
  } else if (b < 12288) {
    int l = b - 12032; wtrans_tile(Wqu, W3t, 256, 1024, l & 31, l >> 5, tid);
  } else if (b < 12544) {
    int l = b - 12288; wtrans_tile(Wrq, W3t + 1024 * 256, 256, 1024, l & 31, l >> 5, tid);
  } else {
    int l = b - 12544; wtrans_tile(Wo, Wo_t, 2048, 2048, l & 63, l >> 6, tid);
  }
}

// ---------------- bf16 MFMA GEMM, swizzled staging: C = A @ Bt^T -----------
__device__ __forceinline__ void cstore(float v, float* p) { *p = v; }
__device__ __forceinline__ void cstore(float v, short* p) { *p = f2bs(v); }

template <typename CT>
__global__ __launch_bounds__(256) void gemm_bt(const short* __restrict__ A, int lda,
                                               const short* __restrict__ Bt, int ldb,
                                               CT* __restrict__ C, int ldc, int K) {
  __shared__ short As[128 * 32];
  __shared__ short Bs[128 * 32];
  const int tid = threadIdx.x;
  const int wave = tid >> 6, lane = tid & 63;
  const int quad = lane >> 4, l15 = lane & 15;
  const int wm = wave & 1, wn = wave >> 1;
  const int row0 = blockIdx.y * 128, col0 = blockIdx.x * 128;
  const int ar = tid >> 2;
  const int ac = (((tid & 3) ^ ((tid >> 2) & 3) ^ ((tid >> 4) & 3))) * 8;
  const short* Ag = A + (size_t)(row0 + ar) * lda + ac;
  const short* Bg = Bt + (size_t)(col0 + ar) * ldb + ac;
  const int sw = ((quad ^ (l15 & 3) ^ ((l15 >> 2) & 3))) * 8;

  f32x4 acc[4][4];
#pragma unroll
  for (int i = 0; i < 4; ++i)
#pragma unroll
    for (int j = 0; j < 4; ++j) acc[i][j] = {0.f, 0.f, 0.f, 0.f};

  for (int k0 = 0; k0 < K; k0 += 32) {
    __syncthreads();
    async16(Ag + k0, &As[tid * 8]);
    async16(Ag + (size_t)64 * lda + k0, &As[2048 + tid * 8]);
    async16(Bg + k0, &Bs[tid * 8]);
    async16(Bg + (size_t)64 * ldb + k0, &Bs[2048 + tid * 8]);
    wait_vm0();
    __syncthreads();
    bf16x8 af[4], bfr[4];
#pragma unroll
    for (int i = 0; i < 4; ++i) {
      af[i]  = *(const bf16x8*)&As[(wm * 64 + i * 16 + l15) * 32 + sw];
      bfr[i] = *(const bf16x8*)&Bs[(wn * 64 + i * 16 + l15) * 32 + sw];
    }
#pragma unroll
    for (int i = 0; i < 4; ++i)
#pragma unroll
      for (int j = 0; j < 4; ++j)
        acc[i][j] = MFMA16(af[i], bfr[j], acc[i][j]);
  }
#pragma unroll
  for (int i = 0; i < 4; ++i)
#pragma unroll
    for (int j = 0; j < 4; ++j)
#pragma unroll
      for (int r = 0; r < 4; ++r) {
        int row = row0 + wm * 64 + i * 16 + quad * 4 + r;
        int col = col0 + wn * 64 + j * 16 + l15;
        cstore(acc[i][j][r], &C[(size_t)row * ldc + col]);
      }
}

// ---------------- RoPE + concat + head-major pack (bf16) -------------------
__global__ __launch_bounds__(256) void rope_pack(
    const short* __restrict__ c3, const short* __restrict__ c2,
    const short* __restrict__ c1, short* __restrict__ qf,
    short* __restrict__ kf) {
  const float QSCALE = 0.08838834764831845f * 1.4426950408889634f;
  int idx = blockIdx.x * 256 + threadIdx.x;
  int m = idx >> 11;
  int col = idx & 2047;
  int h = col >> 7;
  int j = col & 127;
  int b = m >> 11, s = m & 2047;
  float oq, ok;
  if (j < 64) {
    oq = bs2f(c3[(size_t)m * 2048 + h * 64 + j]);
    ok = bs2f(c2[(size_t)m * 3072 + h * 64 + j]);
  } else {
    int jr = j - 64;
    int f = jr & 31;
    float ang = (float)s * __expf(-0.2878231366242557f * (float)f);
    float c = __cosf(ang), sn = __sinf(ang);
    size_t qb = (size_t)m * 2048 + 1024 + h * 64;
    size_t kb = (size_t)m * 1536 + 512 + h * 64;
    float xq = bs2f(c3[qb + jr]), xk = bs2f(c1[kb + jr]);
    float rq, rk;
    if (jr < 32) { rq = -bs2f(c3[qb + jr + 32]); rk = -bs2f(c1[kb + jr + 32]); }
    else         { rq =  bs2f(c3[qb + jr - 32]); rk =  bs2f(c1[kb + jr - 32]); }
    oq = fmaf(xq, c, rq * sn);
    ok = fmaf(xk, c, rk * sn);
  }
  size_t dst = (((size_t)b * 16 + h) * 2048 + s) * 128 + j;
  qf[dst] = f2bs(oq * QSCALE);
  kf[dst] = f2bs(ok);
}

// ---------------- V transpose: C2 col 1024 (ld 3072) -> vt(b,h,128,s) ------
__global__ __launch_bounds__(256) void vtrans(const short* __restrict__ c2,
                                              short* __restrict__ vt) {
  __shared__ short t[64][72];
  int s0 = blockIdx.x * 64, d0 = blockIdx.y * 64, bh = blockIdx.z;
  int b = bh >> 4, h = bh & 15;
#pragma unroll
  for (int i = 0; i < 16; ++i) {
    int idx = threadIdx.x + i * 256;
    int r = idx >> 6, c = idx & 63;
    t[r][c] = c2[(size_t)(b * 2048 + s0 + r) * 3072 + 1024 + h * 128 + d0 + c];
  }
  __syncthreads();
#pragma unroll
  for (int i = 0; i < 16; ++i) {
    int idx = threadIdx.x + i * 256;
    int r = idx >> 6, c = idx & 63;
    vt[((size_t)bh * 128 + d0 + r) * 2048 + s0 + c] = t[c][r];
  }
}

// ---------------- balanced split-K flash attention -------------------------
// LDS double-buffer: async DMA tile k+1 into buf B while computing tile k on
// buf A; vmcnt(0)+one barrier after compute. XCD-local bh mapping.
__global__ __launch_bounds__(256) void attn_split(const short* __restrict__ qf,
                                                  const short* __restrict__ kf,
                                                  const short* __restrict__ vt,
                                                  short* __restrict__ part,
                                                  float2* __restrict__ ml) {
  __shared__ short Ks[2][64 * 128];  // [kpos][d], chunk-swizzled
  __shared__ short Vs[2][128 * 64];  // [d][kpos], chunk-swizzled
  __shared__ short Pw[4][32 * 64];   // per-wave P, stride 64, 3-bit XOR swz
  const int lid = blockIdx.x;
  const int bh = (lid & 7) * 4 + ((lid >> 3) & 3);  // 4 bh per XCD
  const int x = lid >> 5;
  const int tid = threadIdx.x;
  const int wave = tid >> 6, lane = tid & 63;
  const int quad = lane >> 4, l15 = lane & 15;
  const int krow_l = tid >> 4;
  const int kcol_sw = ((tid & 15) ^ krow_l) * 8;
  const int vrow_l = tid >> 3;
  const int vcol_sw = ((tid & 7) ^ (vrow_l & 7)) * 8;
  const short* kgB = kf + (((size_t)bh * 2048) + krow_l) * 128 + kcol_sw;
  const short* vgB = vt + ((size_t)bh * 128 + vrow_l) * 2048 + vcol_sw;
  const int pswz = l15 & 14;  // XOR on 8B-chunk index bits 1..3

  for (int pass = 0; pass < 2; ++pass) {
    const int qt = pass == 0 ? x : 15 - x;
    const int ks = pass == 0 ? 0 : qt + 1;
    const int ke = (qt + 1) << pass;
    const int q0w = qt * 128 + wave * 32;

    bf16x8 qfr[2][4];
#pragma unroll
    for (int mi = 0; mi < 2; ++mi) {
      const short* qp = qf + (((size_t)bh * 2048) + q0w + mi * 16 + l15) * 128;
#pragma unroll
      for (int kc = 0; kc < 4; ++kc)
        qfr[mi][kc] = *(const bf16x8*)(qp + kc * 32 + quad * 8);
    }
    float m_i[2] = {-INFINITY, -INFINITY};
    float l_i[2] = {0.f, 0.f};
    f32x4 O[2][8];
#pragma unroll
    for (int mi = 0; mi < 2; ++mi)
#pragma unroll
      for (int dt = 0; dt < 8; ++dt) O[mi][dt] = {0.f, 0.f, 0.f, 0.f};

    // prologue: stage first tile into buf 0
    {
      const short* kg = kgB + (size_t)ks * 64 * 128;
      const short* vg = vgB + ks * 64;
#pragma unroll
      for (int i = 0; i < 4; ++i) {
        async16(kg + (size_t)i * 16 * 128, &Ks[0][i * 2048 + tid * 8]);
        async16(vg + (size_t)i * 32 * 2048, &Vs[0][i * 2048 + tid * 8]);
      }
    }
    wait_vm0();
    __syncthreads();

    int cur = 0;
    for (int kt = ks; kt < ke; ++kt) {
      const int k0 = kt * 64;
      if (kt + 1 < ke) {  // DMA next tile into the other buffer (no barrier)
        const short* kg = kgB + (size_t)(k0 + 64) * 128;
        const short* vg = vgB + (k0 + 64);
#pragma unroll
        for (int i = 0; i < 4; ++i) {
          async16(kg + (size_t)i * 16 * 128, &Ks[cur ^ 1][i * 2048 + tid * 8]);
          async16(vg + (size_t)i * 32 * 2048, &Vs[cur ^ 1][i * 2048 + tid * 8]);
        }
      }

      // S^T = K @ Q^T  (m=kpos 64, n=qrow 32); lane col l15 = q-row
      f32x4 St[2][4];
#pragma unroll
      for (int mi = 0; mi < 2; ++mi)
#pragma unroll
        for (int j = 0; j < 4; ++j) St[mi][j] = {0.f, 0.f, 0.f, 0.f};
#pragma unroll
      for (int kc = 0; kc < 4; ++kc) {
        bf16x8 kb[4];
#pragma unroll
        for (int j = 0; j < 4; ++j)
          kb[j] = *(const bf16x8*)&Ks[cur][(j * 16 + l15) * 128 +
                                          (((kc * 4 + quad) ^ l15) & 15) * 8];
#pragma unroll
        for (int mi = 0; mi < 2; ++mi)
#pragma unroll
          for (int j = 0; j < 4; ++j)
            St[mi][j] = MFMA16(kb[j], qfr[mi][kc], St[mi][j]);
      }

      if (kt >= 2 * qt) {  // diagonal: causal mask
#pragma unroll
        for (int mi = 0; mi < 2; ++mi)
#pragma unroll
          for (int j = 0; j < 4; ++j)
#pragma unroll
            for (int r = 0; r < 4; ++r)
              if (k0 + j * 16 + quad * 4 + r > q0w + mi * 16 + l15)
                St[mi][j][r] = -INFINITY;
      }

      float alpha[2];
#pragma unroll
      for (int mi = 0; mi < 2; ++mi) {
        float mt = -INFINITY;
#pragma unroll
        for (int j = 0; j < 4; ++j)
#pragma unroll
          for (int r = 0; r < 4; ++r) mt = fmaxf(mt, St[mi][j][r]);
        mt = fmaxf(mt, __shfl_xor(mt, 16));
        mt = fmaxf(mt, __shfl_xor(mt, 32));
        float mold = m_i[mi];
        float mnew = fmaxf(mold, mt);
        float msafe = (mnew == -INFINITY) ? 0.f : mnew;
        alpha[mi] = __builtin_amdgcn_exp2f(mold - msafe);
        float ps = 0.f;
#pragma unroll
        for (int j = 0; j < 4; ++j)
#pragma unroll
          for (int r = 0; r < 4; ++r) {
            float p = __builtin_amdgcn_exp2f(St[mi][j][r] - msafe);
            St[mi][j][r] = p;
            ps += p;
          }
        ps += __shfl_xor(ps, 16);
        ps += __shfl_xor(ps, 32);
        m_i[mi] = mnew;
        l_i[mi] = l_i[mi] * alpha[mi] + ps;
#pragma unroll
        for (int dt = 0; dt < 8; ++dt)
#pragma unroll
          for (int r = 0; r < 4; ++r) O[mi][dt][r] *= alpha[mi];
      }

      // P (truncated bf16) -> per-wave LDS, stride 64, chunk-XOR swizzle
#pragma unroll
      for (int mi = 0; mi < 2; ++mi) {
        int pr = mi * 16 + l15;
#pragma unroll
        for (int j = 0; j < 4; ++j) {
          u32 u0 = (fbits(St[mi][j][1]) & 0xffff0000u) | (fbits(St[mi][j][0]) >> 16);
          u32 u1 = (fbits(St[mi][j][3]) & 0xffff0000u) | (fbits(St[mi][j][2]) >> 16);
          uint2 pk; pk.x = u0; pk.y = u1;
          int c8s = (j * 4 + quad) ^ pswz;
          *(uint2*)&Pw[wave][pr * 64 + c8s * 4] = pk;
        }
      }

      // O^T += V^T-frag @ P-frag
#pragma unroll
      for (int kc2 = 0; kc2 < 2; ++kc2) {
        bf16x8 pa[2];
#pragma unroll
        for (int mi = 0; mi < 2; ++mi) {
          int pr = mi * 16 + l15;
          int c8s = (kc2 * 8 + quad * 2) ^ pswz;
          pa[mi] = *(const bf16x8*)&Pw[wave][pr * 64 + c8s * 4];
        }
#pragma unroll
        for (int dt = 0; dt < 8; ++dt) {
          bf16x8 vb = *(const bf16x8*)&Vs[cur][(dt * 16 + l15) * 64 +
                                              (((kc2 * 4 + quad) ^ (l15 & 7)) & 7) * 8];
#pragma unroll
          for (int mi = 0; mi < 2; ++mi)
            O[mi][dt] = MFMA16(vb, pa[mi], O[mi][dt]);
        }
      }

      wait_vm0();       // next tile's DMA done (overlapped by compute above)
      __syncthreads();  // all waves done reading cur + all DMAs drained
      cur ^= 1;
    }

    // store partial O as bf16: [qrow][d]
    const int pidx = (bh * 16 + qt) * 2 + pass;
    short* pb = part + (size_t)pidx * 128 * 128;
#pragma unroll
    for (int mi = 0; mi < 2; ++mi) {
      int qrow = wave * 32 + mi * 16 + l15;
#pragma unroll
      for (int dt = 0; dt < 8; ++dt) {
        short4 o;
        o.x = f2bs(O[mi][dt][0]); o.y = f2bs(O[mi][dt][1]);
        o.z = f2bs(O[mi][dt][2]); o.w = f2bs(O[mi][dt][3]);
        *(short4*)&pb[(size_t)qrow * 128 + dt * 16 + quad * 4] = o;
      }
    }
    if (quad == 0) {
#pragma unroll
      for (int mi = 0; mi < 2; ++mi) {
        float2 v; v.x = m_i[mi]; v.y = l_i[mi];
        ml[pidx * 128 + wave * 32 + mi * 16 + l15] = v;
      }
    }
  }
}

// ---------------- merge two partials per q-tile ----------------------------
__global__ __launch_bounds__(256) void attn_merge(const short* __restrict__ part,
                                                  const float2* __restrict__ ml,
                                                  short* __restrict__ y) {
  const int qt = blockIdx.x, bh = blockIdx.y;
  const int b = bh >> 4, h = bh & 15;
  const int row = threadIdx.x >> 1, d0 = (threadIdx.x & 1) * 64;
  const int p1 = (bh * 16 + qt) * 2, p2 = p1 + 1;
  float2 a = ml[p1 * 128 + row], c = ml[p2 * 128 + row];
  float m = fmaxf(a.x, c.x);
  float a1 = __builtin_amdgcn_exp2f(a.x - m);
  float a2 = __builtin_amdgcn_exp2f(c.x - m);
  float invl = 1.f / (a.y * a1 + c.y * a2);
  a1 *= invl; a2 *= invl;
  const short* s1 = part + ((size_t)p1 * 128 + row) * 128 + d0;
  const short* s2 = part + ((size_t)p2 * 128 + row) * 128 + d0;
  short* yp = y + (((size_t)b * 2048 + qt * 128 + row) * 16 + h) * 128 + d0;
#pragma unroll
  for (int j = 0; j < 16; ++j) {
    short4 v1 = *(const short4*)(s1 + j * 4);
    short4 v2 = *(const short4*)(s2 + j * 4);
    short4 o;
    o.x = f2bs(bs2f(v1.x) * a1 + bs2f(v2.x) * a2);
    o.y = f2bs(bs2f(v1.y) * a1 + bs2f(v2.y) * a2);
    o.z = f2bs(bs2f(v1.z) * a1 + bs2f(v2.z) * a2);
    o.w = f2bs(bs2f(v1.w) * a1 + bs2f(v2.w) * a2);
    *(short4*)(yp + j * 4) = o;
  }
}

extern "C" void kernel_launch(void* const* d_in, const int* in_sizes, int n_in,
                              void* d_out, int out_size, void* d_ws, size_t ws_size,
                              hipStream_t stream) {
  const float* hs   = (const float*)d_in[0];
  const float* Wkvd = (const float*)d_in[1];
  const float* Wqd  = (const float*)d_in[2];
  const float* Wku  = (const float*)d_in[3];
  const float* Wqu  = (const float*)d_in[4];
  const float* Wvu  = (const float*)d_in[5];
  const float* Wrk  = (const float*)d_in[6];
  const float* Wrq  = (const float*)d_in[7];
  const float* Wo   = (const float*)d_in[8];
  float* out = (float*)d_out;
  char* ws = (char*)d_ws;
  const size_t MB = 1024ull * 1024ull;

  short* hs_b = (short*)(ws + 0 * MB);     // 16 MB
  short* W1t  = (short*)(ws + 16 * MB);    // (1536,2048): kvd|qd|rk ^T
  short* W2t  = (short*)(ws + 22 * MB);    // (3072,256): ku|vu ^T
  short* W3t  = (short*)(ws + 24 * MB);    // (2048,256): qu|rq ^T
  short* C1   = (short*)(ws + 25 * MB);    // (4096,1536): kv_d|q_d|k_r
  short* C2   = (short*)(ws + 37 * MB);    // (4096,3072): k_c|v
  short* C3   = (short*)(ws + 61 * MB);    // (4096,2048): q_c|q_r
  short* Wo_t = (short*)(ws + 77 * MB);    // (2048,2048)
  short* q_f  = (short*)(ws + 85 * MB);    // (32,2048,128)
  short* k_f  = (short*)(ws + 101 * MB);
  short* v_t  = (short*)(ws + 117 * MB);   // (32,128,2048)
  short* y_b  = (short*)(ws + 133 * MB);   // (b,s,h,d)
  short*  partb = (short*)(ws + 0 * MB);   // overlay: 1024x128x128 bf16 (32 MB)
  float2* mlb   = (float2*)(ws + 32 * MB); // 1 MB

  dim3 blk(256);
  prep_all<<<dim3(16640), blk, 0, stream>>>(hs, Wkvd, Wqd, Wku, Wqu, Wvu, Wrk,
                                            Wrq, Wo, hs_b, W1t, W2t, W3t, Wo_t);

  gemm_bt<short><<<dim3(12, 32), blk, 0, stream>>>(hs_b, 2048, W1t, 2048, C1, 1536, 2048);
  gemm_bt<short><<<dim3(24, 32), blk, 0, stream>>>(C1, 1536, W2t, 256, C2, 3072, 256);
  gemm_bt<short><<<dim3(16, 32), blk, 0, stream>>>(C1 + 256, 1536, W3t, 256, C3, 2048, 256);

  rope_pack<<<dim3(32768), blk, 0, stream>>>(C3, C2, C1, q_f, k_f);
  vtrans<<<dim3(32, 2, 32), blk, 0, stream>>>(C2, v_t);

  attn_split<<<dim3(512), blk, 0, stream>>>(q_f, k_f, v_t, partb, mlb);
  attn_merge<<<dim3(16, 32), blk, 0, stream>>>(partb, mlb, y_b);

  gemm_bt<float><<<dim3(16, 32), blk, 0, stream>>>(y_b, 2048, Wo_t, 2048, out, 2048, 2048);
}